// Round 1
// baseline (570.906 us; speedup 1.0000x reference)
//
#include <hip/hip_runtime.h>
#include <stdint.h>

#define B_ROWS 2048
#define C_CLS  9605
#define L_GRP  20
#define WAVES  4
#define UNROLL 8

__device__ __forceinline__ float sigmoidf(float v) {
  return 1.0f / (1.0f + __expf(-v));
}

// our_rank_loss: d = x2-x1+0.05; s = sigmoid(10*d); d>0 ? 2*s : s
__device__ __forceinline__ float rank_loss(float x1, float x2) {
  float d = x2 - x1 + 0.05f;
  float s = 1.0f / (1.0f + __expf(-10.0f * d));
  return d > 0.0f ? 2.0f * s : s;
}

// order-preserving float<->uint mapping (for unsigned atomicMax on floats)
__device__ __forceinline__ unsigned fmap(float f) {
  unsigned u = __float_as_uint(f);
  return (u & 0x80000000u) ? ~u : (u | 0x80000000u);
}
__device__ __forceinline__ float funmap(unsigned m) {
  unsigned u = (m & 0x80000000u) ? (m ^ 0x80000000u) : ~m;
  return __uint_as_float(u);
}

// group_mask may arrive as 1-byte bools or 4-byte ints/floats. Count nonzero
// bytes in the first L*C bytes (safe under both layouts):
//   1-byte layout -> exactly L*G = 1000 nonzero bytes
//   int32 layout  -> first L*C bytes == rows 0..4 -> 250 nonzero bytes
//   fp32 layout   -> 500 nonzero bytes
__global__ void detect_layout_kernel(const unsigned char* gm, int nbytes, int* flag) {
  __shared__ int cnt;
  if (threadIdx.x == 0) cnt = 0;
  __syncthreads();
  int local = 0;
  for (int i = threadIdx.x; i < nbytes; i += blockDim.x) local += (gm[i] != 0);
  atomicAdd(&cnt, local);
  __syncthreads();
  if (threadIdx.x == 0) *flag = (cnt > 600) ? 1 : 4;
}

__global__ void init_gid_kernel(unsigned char* gid) {
  int i = blockIdx.x * blockDim.x + threadIdx.x;
  if (i < C_CLS) gid[i] = 0xFF;
}

__global__ void build_gid_kernel(const void* gm, const int* __restrict__ flag,
                                 unsigned char* __restrict__ gid) {
  int i = blockIdx.x * blockDim.x + threadIdx.x;
  if (i >= L_GRP * C_CLS) return;
  bool m;
  if (*flag == 1) m = ((const unsigned char*)gm)[i] != 0;
  else            m = ((const unsigned int*)gm)[i] != 0u;
  if (m) {
    int l = i / C_CLS;
    int c = i - l * C_CLS;
    gid[c] = (unsigned char)l;  // groups are disjoint -> no race
  }
}

__global__ __launch_bounds__(WAVES * 64) void loss_kernel(
    const float* __restrict__ x, const int* __restrict__ y,
    const int* __restrict__ yn, const unsigned char* __restrict__ gid,
    float* __restrict__ out) {
  __shared__ unsigned s_gmax[WAVES][L_GRP];
  const int lane = threadIdx.x & 63;
  const int wave = threadIdx.x >> 6;
  const int row  = blockIdx.x * WAVES + wave;  // grid = B/WAVES exactly

  const float* xr = x  + (size_t)row * C_CLS;
  const int*   yr = y  + (size_t)row * C_CLS;
  const int*   nr = yn + (size_t)row * C_CLS;

  if (lane < L_GRP) s_gmax[wave][lane] = 0u;  // 0 < fmap(any real float)

  float t[11];  // per-lane top-11 of raw x, descending
#pragma unroll
  for (int i = 0; i < 11; ++i) t[i] = -3.0e38f;
  unsigned actL = 0u, actnL = 0u;

  const int CM = (C_CLS / (64 * UNROLL)) * (64 * UNROLL);  // 9216
  for (int c = lane; c < CM; c += 64 * UNROLL) {
    float xv[UNROLL]; int yv[UNROLL]; int nv[UNROLL]; unsigned char gv[UNROLL];
#pragma unroll
    for (int k = 0; k < UNROLL; ++k) {
      int cc = c + 64 * k;
      xv[k] = xr[cc]; yv[k] = yr[cc]; nv[k] = nr[cc]; gv[k] = gid[cc];
    }
#pragma unroll
    for (int k = 0; k < UNROLL; ++k) {
      float v = xv[k];
      if (v > t[10]) {  // sorted insert (bubble pass keeps descending order)
        float a = v;
#pragma unroll
        for (int i = 0; i < 11; ++i) { float hi = fmaxf(t[i], a); a = fminf(t[i], a); t[i] = hi; }
      }
      if (gv[k] < L_GRP) {
        atomicMax(&s_gmax[wave][gv[k]], fmap(v));
        unsigned bit = 1u << gv[k];
        if (yv[k] != 0) actL  |= bit;
        if (nv[k] != 0) actnL |= bit;
      }
    }
  }
  for (int c = CM + lane; c < C_CLS; c += 64) {  // tail (389 elements)
    float v = xr[c];
    unsigned char gk = gid[c];
    int yv = yr[c], nv = nr[c];
    if (v > t[10]) {
      float a = v;
#pragma unroll
      for (int i = 0; i < 11; ++i) { float hi = fmaxf(t[i], a); a = fminf(t[i], a); t[i] = hi; }
    }
    if (gk < L_GRP) {
      atomicMax(&s_gmax[wave][gk], fmap(v));
      unsigned bit = 1u << gk;
      if (yv != 0) actL  |= bit;
      if (nv != 0) actnL |= bit;
    }
  }

  // OR-reduce active-group masks across the wave (no LDS needed)
#pragma unroll
  for (int off = 32; off; off >>= 1) {
    actL  |= __shfl_xor(actL,  off);
    actnL |= __shfl_xor(actnL, off);
  }

  // wave-level 11th largest: 11 rounds of max-extract from 64 sorted lists
  float cur = t[0];
  float eleventh = -3.0e38f;
#pragma unroll
  for (int r = 0; r < 11; ++r) {
    float m = cur;
#pragma unroll
    for (int off = 32; off; off >>= 1) m = fmaxf(m, __shfl_xor(m, off));
    eleventh = m;
    if (r < 10) {
      unsigned long long b = __ballot(cur == m);
      int leader = (int)(__ffsll(b) - 1);
      if (lane == leader) {  // leader pops its head
#pragma unroll
        for (int i = 0; i < 10; ++i) t[i] = t[i + 1];
        t[10] = -3.0e38f;
        cur = t[0];
      }
    }
  }

  __syncthreads();  // make per-wave LDS atomics safely visible before readback

  const bool has_gt = (actL != 0u);
  const int g = has_gt ? (__ffs(actL) - 1) : 0;  // argmax of bool = first active
  const float thres = fmaxf(sigmoidf(eleventh), 0.5f);

  float union_max = -3.0e38f, gt_sg = 0.0f, inc_max = -3.0e38f, inc_neg = 0.0f;
#pragma unroll
  for (int l = 0; l < L_GRP; ++l) {
    float sg = sigmoidf(funmap(s_gmax[wave][l]));
    union_max = fmaxf(union_max, sg);
    if (l == g) gt_sg = sg; else inc_max = fmaxf(inc_max, sg);
    if ((actnL >> l) & 1u) inc_neg = fmaxf(inc_neg, sg);
  }
  inc_max = fmaxf(inc_max, 0.0f);
  inc_neg = fmaxf(inc_neg, 0.0f);

  float loss;
  if (has_gt) {
    loss = rank_loss(gt_sg, thres);
    if (inc_max > 0.0f) loss += 0.5f * rank_loss(thres, inc_max);
    loss += 0.5f * rank_loss(thres, (inc_neg > 0.0f) ? inc_neg : inc_max);
  } else {
    loss = 0.5f * rank_loss(thres, union_max) + 0.5f * rank_loss(thres, inc_neg);
  }
  if (lane == 0) atomicAdd(out, loss);
}

extern "C" void kernel_launch(void* const* d_in, const int* in_sizes, int n_in,
                              void* d_out, int out_size, void* d_ws, size_t ws_size,
                              hipStream_t stream) {
  (void)in_sizes; (void)n_in; (void)ws_size;
  const float* x  = (const float*)d_in[0];
  const int*   y  = (const int*)d_in[1];
  const int*   yn = (const int*)d_in[2];
  const void*  gm = d_in[3];

  int* flag = (int*)d_ws;
  unsigned char* gid = (unsigned char*)d_ws + 64;

  detect_layout_kernel<<<1, 256, 0, stream>>>((const unsigned char*)gm,
                                              L_GRP * C_CLS, flag);
  init_gid_kernel<<<(C_CLS + 255) / 256, 256, 0, stream>>>(gid);
  build_gid_kernel<<<(L_GRP * C_CLS + 255) / 256, 256, 0, stream>>>(gm, flag, gid);

  hipMemsetAsync(d_out, 0, (size_t)out_size * sizeof(float), stream);

  loss_kernel<<<B_ROWS / WAVES, WAVES * 64, 0, stream>>>(x, y, yn, gid,
                                                         (float*)d_out);
}

// Round 2
// 264.748 us; speedup vs baseline: 2.1564x; 2.1564x over previous
//
#include <hip/hip_runtime.h>
#include <stdint.h>

#define B_ROWS 2048
#define C_CLS  9605
#define L_GRP  20
#define WAVES  4
#define UNROLL 8

__device__ __forceinline__ float sigmoidf(float v) {
  return 1.0f / (1.0f + __expf(-v));
}

// our_rank_loss: d = x2-x1+0.05; s = sigmoid(10*d); d>0 ? 2*s : s
__device__ __forceinline__ float rank_loss(float x1, float x2) {
  float d = x2 - x1 + 0.05f;
  float s = 1.0f / (1.0f + __expf(-10.0f * d));
  return d > 0.0f ? 2.0f * s : s;
}

// order-preserving float<->uint mapping (for unsigned atomicMax on floats)
__device__ __forceinline__ unsigned fmap(float f) {
  unsigned u = __float_as_uint(f);
  return (u & 0x80000000u) ? ~u : (u | 0x80000000u);
}
__device__ __forceinline__ float funmap(unsigned m) {
  unsigned u = (m & 0x80000000u) ? (m ^ 0x80000000u) : ~m;
  return __uint_as_float(u);
}

// Fused: (a) init gid[] to 0xFF, (b) count nonzero bytes of group_mask's first
// L*C bytes (layout probe: 1000 nonzero -> byte/bool layout, 250/500 -> int32/
// fp32 layout). Parallel grid-stride + wave reduce + one atomicAdd per wave.
// cnt must be zeroed (hipMemsetAsync) before launch.
__global__ void probe_init_kernel(const unsigned char* __restrict__ gm,
                                  unsigned char* __restrict__ gid,
                                  int* __restrict__ cnt) {
  const int tid = blockIdx.x * blockDim.x + threadIdx.x;
  const int nthreads = gridDim.x * blockDim.x;
  for (int i = tid; i < C_CLS; i += nthreads) gid[i] = 0xFF;
  int local = 0;
  for (int i = tid; i < L_GRP * C_CLS; i += nthreads) local += (gm[i] != 0);
#pragma unroll
  for (int off = 32; off; off >>= 1) local += __shfl_xor(local, off);
  if ((threadIdx.x & 63) == 0 && local) atomicAdd(cnt, local);
}

__global__ void build_gid_kernel(const void* gm, const int* __restrict__ cnt,
                                 unsigned char* __restrict__ gid) {
  int i = blockIdx.x * blockDim.x + threadIdx.x;
  if (i >= L_GRP * C_CLS) return;
  const bool is_byte = (*cnt > 600);
  bool m;
  if (is_byte) m = ((const unsigned char*)gm)[i] != 0;
  else         m = ((const unsigned int*)gm)[i] != 0u;
  if (m) {
    int l = i / C_CLS;
    int c = i - l * C_CLS;
    gid[c] = (unsigned char)l;  // groups are disjoint -> no race
  }
}

__global__ __launch_bounds__(WAVES * 64) void loss_kernel(
    const float* __restrict__ x, const int* __restrict__ y,
    const int* __restrict__ yn, const unsigned char* __restrict__ gid,
    float* __restrict__ out) {
  __shared__ unsigned s_gmax[WAVES][L_GRP];
  const int lane = threadIdx.x & 63;
  const int wave = threadIdx.x >> 6;
  const int row  = blockIdx.x * WAVES + wave;  // grid = B/WAVES exactly

  const float* xr = x  + (size_t)row * C_CLS;
  const int*   yr = y  + (size_t)row * C_CLS;
  const int*   nr = yn + (size_t)row * C_CLS;

  if (lane < L_GRP) s_gmax[wave][lane] = 0u;  // 0 < fmap(any real float)

  float t[11];  // per-lane top-11 of raw x, descending
#pragma unroll
  for (int i = 0; i < 11; ++i) t[i] = -3.0e38f;
  unsigned actL = 0u, actnL = 0u;

  const int CM = (C_CLS / (64 * UNROLL)) * (64 * UNROLL);  // 9216
  for (int c = lane; c < CM; c += 64 * UNROLL) {
    float xv[UNROLL]; int yv[UNROLL]; int nv[UNROLL]; unsigned char gv[UNROLL];
#pragma unroll
    for (int k = 0; k < UNROLL; ++k) {
      int cc = c + 64 * k;
      xv[k] = xr[cc]; yv[k] = yr[cc]; nv[k] = nr[cc]; gv[k] = gid[cc];
    }
#pragma unroll
    for (int k = 0; k < UNROLL; ++k) {
      float v = xv[k];
      if (v > t[10]) {  // sorted insert (bubble pass keeps descending order)
        float a = v;
#pragma unroll
        for (int i = 0; i < 11; ++i) { float hi = fmaxf(t[i], a); a = fminf(t[i], a); t[i] = hi; }
      }
      if (gv[k] < L_GRP) {
        atomicMax(&s_gmax[wave][gv[k]], fmap(v));
        unsigned bit = 1u << gv[k];
        if (yv[k] != 0) actL  |= bit;
        if (nv[k] != 0) actnL |= bit;
      }
    }
  }
  for (int c = CM + lane; c < C_CLS; c += 64) {  // tail (389 elements)
    float v = xr[c];
    unsigned char gk = gid[c];
    int yv = yr[c], nv = nr[c];
    if (v > t[10]) {
      float a = v;
#pragma unroll
      for (int i = 0; i < 11; ++i) { float hi = fmaxf(t[i], a); a = fminf(t[i], a); t[i] = hi; }
    }
    if (gk < L_GRP) {
      atomicMax(&s_gmax[wave][gk], fmap(v));
      unsigned bit = 1u << gk;
      if (yv != 0) actL  |= bit;
      if (nv != 0) actnL |= bit;
    }
  }

  // OR-reduce active-group masks across the wave (no LDS needed)
#pragma unroll
  for (int off = 32; off; off >>= 1) {
    actL  |= __shfl_xor(actL,  off);
    actnL |= __shfl_xor(actnL, off);
  }

  // wave-level 11th largest: 11 rounds of max-extract from 64 sorted lists
  float cur = t[0];
  float eleventh = -3.0e38f;
#pragma unroll
  for (int r = 0; r < 11; ++r) {
    float m = cur;
#pragma unroll
    for (int off = 32; off; off >>= 1) m = fmaxf(m, __shfl_xor(m, off));
    eleventh = m;
    if (r < 10) {
      unsigned long long b = __ballot(cur == m);
      int leader = (int)(__ffsll(b) - 1);
      if (lane == leader) {  // leader pops its head
#pragma unroll
        for (int i = 0; i < 10; ++i) t[i] = t[i + 1];
        t[10] = -3.0e38f;
        cur = t[0];
      }
    }
  }

  __syncthreads();  // make per-wave LDS atomics safely visible before readback

  const bool has_gt = (actL != 0u);
  const int g = has_gt ? (__ffs(actL) - 1) : 0;  // argmax of bool = first active
  const float thres = fmaxf(sigmoidf(eleventh), 0.5f);

  float union_max = -3.0e38f, gt_sg = 0.0f, inc_max = -3.0e38f, inc_neg = 0.0f;
#pragma unroll
  for (int l = 0; l < L_GRP; ++l) {
    float sg = sigmoidf(funmap(s_gmax[wave][l]));
    union_max = fmaxf(union_max, sg);
    if (l == g) gt_sg = sg; else inc_max = fmaxf(inc_max, sg);
    if ((actnL >> l) & 1u) inc_neg = fmaxf(inc_neg, sg);
  }
  inc_max = fmaxf(inc_max, 0.0f);
  inc_neg = fmaxf(inc_neg, 0.0f);

  float loss;
  if (has_gt) {
    loss = rank_loss(gt_sg, thres);
    if (inc_max > 0.0f) loss += 0.5f * rank_loss(thres, inc_max);
    loss += 0.5f * rank_loss(thres, (inc_neg > 0.0f) ? inc_neg : inc_max);
  } else {
    loss = 0.5f * rank_loss(thres, union_max) + 0.5f * rank_loss(thres, inc_neg);
  }
  if (lane == 0) atomicAdd(out, loss);
}

extern "C" void kernel_launch(void* const* d_in, const int* in_sizes, int n_in,
                              void* d_out, int out_size, void* d_ws, size_t ws_size,
                              hipStream_t stream) {
  (void)in_sizes; (void)n_in; (void)ws_size;
  const float* x  = (const float*)d_in[0];
  const int*   y  = (const int*)d_in[1];
  const int*   yn = (const int*)d_in[2];
  const void*  gm = d_in[3];

  int* cnt = (int*)d_ws;
  unsigned char* gid = (unsigned char*)d_ws + 64;

  hipMemsetAsync(d_ws, 0, 64, stream);
  probe_init_kernel<<<188, 256, 0, stream>>>((const unsigned char*)gm, gid, cnt);
  build_gid_kernel<<<(L_GRP * C_CLS + 255) / 256, 256, 0, stream>>>(gm, cnt, gid);

  hipMemsetAsync(d_out, 0, (size_t)out_size * sizeof(float), stream);

  loss_kernel<<<B_ROWS / WAVES, WAVES * 64, 0, stream>>>(x, y, yn, gid,
                                                         (float*)d_out);
}

// Round 3
// 252.825 us; speedup vs baseline: 2.2581x; 1.0472x over previous
//
#include <hip/hip_runtime.h>
#include <stdint.h>

#define B_ROWS 2048
#define C_CLS  9605
#define L_GRP  20
#define GM_BYTES (L_GRP * C_CLS) /* 192100 */
#define REPSTRIDE 9728           /* multiple of 4, > C_CLS */
#define NEG_BIG -3.0e38f

__device__ __forceinline__ float sigmoidf(float v) {
  return 1.0f / (1.0f + __expf(-v));
}

// our_rank_loss: d = x2-x1+0.05; s = sigmoid(10*d); d>0 ? 2*s : s
__device__ __forceinline__ float rank_loss(float x1, float x2) {
  float d = x2 - x1 + 0.05f;
  float s = 1.0f / (1.0f + __expf(-10.0f * d));
  return d > 0.0f ? 2.0f * s : s;
}

// order-preserving float<->uint mapping (unsigned atomicMax on floats)
__device__ __forceinline__ unsigned fmap(float f) {
  unsigned u = __float_as_uint(f);
  return (u & 0x80000000u) ? ~u : (u | 0x80000000u);
}
__device__ __forceinline__ float funmap(unsigned m) {
  unsigned u = (m & 0x80000000u) ? (m ^ 0x80000000u) : ~m;
  return __uint_as_float(u);
}

// ws layout: [0..63] flag ; [64 ...] 4 byte-shifted gid copies, copy m at
// ws + 64 + m*REPSTRIDE + m  (so (copy_m + peel) is 4B-aligned for rows with
// (row*C)&3 == m). Single-block fused kernel: zero d_out, 0xFF-init the gid
// region, vector-count nonzero bytes of group_mask's first L*C bytes
// (1000 -> byte/bool layout; 250 int32 / 500 fp32 -> 4-byte layout).
__global__ void probe_init_kernel(const uint4* __restrict__ gm,
                                  unsigned char* __restrict__ ws,
                                  float* __restrict__ out,
                                  int* __restrict__ flag) {
  __shared__ int s_part[16];
  const int tid = threadIdx.x;  // 1024 threads
  if (tid == 0) out[0] = 0.0f;
  const int initbytes = 3 * REPSTRIDE + C_CLS + 16;
  for (int i = tid; i < initbytes; i += 1024) ws[64 + i] = 0xFF;
  int local = 0;
  const int nvec = GM_BYTES / 16;  // 12006 (tail = 4 bytes)
  for (int i = tid; i < nvec; i += 1024) {
    uint4 w = gm[i];
    unsigned a[4] = {w.x, w.y, w.z, w.w};
#pragma unroll
    for (int q = 0; q < 4; ++q) {
      local += ((a[q] & 0x000000FFu) != 0) + ((a[q] & 0x0000FF00u) != 0) +
               ((a[q] & 0x00FF0000u) != 0) + ((a[q] & 0xFF000000u) != 0);
    }
  }
  if (tid == 0) {
    const unsigned char* gb = (const unsigned char*)gm;
    for (int i = nvec * 16; i < GM_BYTES; ++i) local += (gb[i] != 0);
  }
#pragma unroll
  for (int off = 32; off; off >>= 1) local += __shfl_xor(local, off);
  if ((tid & 63) == 0) s_part[tid >> 6] = local;
  __syncthreads();
  if (tid == 0) {
    int tot = 0;
    for (int w = 0; w < 16; ++w) tot += s_part[w];
    *flag = tot;
  }
}

__global__ void build_gid_kernel(const void* gm, const int* __restrict__ flag,
                                 unsigned char* __restrict__ ws) {
  int i = blockIdx.x * blockDim.x + threadIdx.x;
  if (i >= GM_BYTES) return;
  const bool is_byte = (*flag > 600);
  bool m;
  if (is_byte) m = ((const unsigned char*)gm)[i] != 0;
  else         m = ((const unsigned int*)gm)[i] != 0u;
  if (m) {
    int l = i / C_CLS;
    int c = i - l * C_CLS;
    unsigned char* base = ws + 64;
#pragma unroll
    for (int r = 0; r < 4; ++r) base[r * REPSTRIDE + r + c] = (unsigned char)l;
  }
}

__global__ __launch_bounds__(256, 4) void loss_kernel(
    const float* __restrict__ x, const int* __restrict__ y,
    const int* __restrict__ yn, const unsigned char* __restrict__ ws64,
    float* __restrict__ out) {
  __shared__ unsigned s_gmax[L_GRP];
  __shared__ unsigned s_act, s_actn;
  __shared__ float s_wtop[4 * 11];
  const int tid = threadIdx.x;
  const int lane = tid & 63;
  const int wave = tid >> 6;
  const int row = blockIdx.x;  // grid = B_ROWS

  const size_t base = (size_t)row * C_CLS;
  const int mis = (int)(base & 3);
  const int peel = (4 - mis) & 3;
  const float* xr = x + base;
  const int* yr = y + base;
  const int* nr = yn + base;
  const unsigned char* gidc = ws64 + mis * REPSTRIDE + mis;  // gidc[c]=gid[c]

  if (tid < L_GRP) s_gmax[tid] = 0u;  // 0 < fmap(any real float)
  if (tid == 0) { s_act = 0u; s_actn = 0u; }
  __syncthreads();

  float t[11];  // per-thread top-11 of raw x, descending
#pragma unroll
  for (int i = 0; i < 11; ++i) t[i] = NEG_BIG;
  unsigned actL = 0u, actnL = 0u;

  auto process = [&](float v, unsigned gk, int yv, int nv) {
    if (v > t[10]) {  // sorted insert
      float a = v;
#pragma unroll
      for (int i = 0; i < 11; ++i) {
        float hi = fmaxf(t[i], a); a = fminf(t[i], a); t[i] = hi;
      }
    }
    if (gk < L_GRP) {
      atomicMax(&s_gmax[gk], fmap(v));
      unsigned bit = 1u << gk;
      if (yv != 0) actL |= bit;
      if (nv != 0) actnL |= bit;
    }
  };

  if (tid < peel) process(xr[tid], gidc[tid], yr[tid], nr[tid]);

  const int nvec = (C_CLS - peel) >> 2;
  const float4* x4 = (const float4*)(xr + peel);
  const int4* y4 = (const int4*)(yr + peel);
  const int4* n4 = (const int4*)(nr + peel);
  const unsigned* g4 = (const unsigned*)(gidc + peel);
  for (int j = tid; j < nvec; j += 256) {
    float4 xv = x4[j];
    int4 yv = y4[j];
    int4 nv = n4[j];
    unsigned gw = g4[j];
    process(xv.x, gw & 0xFFu, yv.x, nv.x);
    process(xv.y, (gw >> 8) & 0xFFu, yv.y, nv.y);
    process(xv.z, (gw >> 16) & 0xFFu, yv.z, nv.z);
    process(xv.w, gw >> 24, yv.w, nv.w);
  }
  const int tail0 = peel + (nvec << 2);
  const int rem = C_CLS - tail0;  // 0..3
  if (tid < rem) {
    int c = tail0 + tid;
    process(xr[c], gidc[c], yr[c], nr[c]);
  }

  if (actL) atomicOr(&s_act, actL);    // rare (~1 positive/row)
  if (actnL) atomicOr(&s_actn, actnL);

  // wave top-11: 11 rounds of max-extract from 64 sorted per-lane lists
  float cur = t[0];
  float mr[11];
#pragma unroll
  for (int r = 0; r < 11; ++r) {
    float m = cur;
#pragma unroll
    for (int off = 32; off; off >>= 1) m = fmaxf(m, __shfl_xor(m, off));
    mr[r] = m;
    if (r < 10) {
      unsigned long long b = __ballot(cur == m);
      int leader = (int)(__ffsll(b) - 1);
      if (lane == leader) {
#pragma unroll
        for (int i = 0; i < 10; ++i) t[i] = t[i + 1];
        t[10] = NEG_BIG;
        cur = t[0];
      }
    }
  }
  if (lane == 0) {
#pragma unroll
    for (int r = 0; r < 11; ++r) s_wtop[wave * 11 + r] = mr[r];
  }
  __syncthreads();  // also publishes s_gmax / s_act / s_actn

  if (wave == 0) {
    // merge 4 waves' sorted top-11 (44 candidates): 11 extract rounds
    float v = (lane < 44) ? s_wtop[lane] : NEG_BIG;
    float eleventh = NEG_BIG;
#pragma unroll
    for (int r = 0; r < 11; ++r) {
      float m = v;
#pragma unroll
      for (int off = 32; off; off >>= 1) m = fmaxf(m, __shfl_xor(m, off));
      eleventh = m;
      if (r < 10) {
        unsigned long long b = __ballot(v == m);
        int leader = (int)(__ffsll(b) - 1);
        if (lane == leader) v = NEG_BIG;
      }
    }

    const unsigned aL = s_act, anL = s_actn;
    const bool has_gt = (aL != 0u);
    const int g = has_gt ? (__ffs(aL) - 1) : 0;  // argmax of bool = first
    const float thres = fmaxf(sigmoidf(eleventh), 0.5f);

    float union_max = NEG_BIG, gt_sg = 0.0f, inc_max = NEG_BIG, inc_neg = 0.0f;
#pragma unroll
    for (int l = 0; l < L_GRP; ++l) {
      float sg = sigmoidf(funmap(s_gmax[l]));
      union_max = fmaxf(union_max, sg);
      if (l == g) gt_sg = sg; else inc_max = fmaxf(inc_max, sg);
      if ((anL >> l) & 1u) inc_neg = fmaxf(inc_neg, sg);
    }
    inc_max = fmaxf(inc_max, 0.0f);
    inc_neg = fmaxf(inc_neg, 0.0f);

    float loss;
    if (has_gt) {
      loss = rank_loss(gt_sg, thres);
      if (inc_max > 0.0f) loss += 0.5f * rank_loss(thres, inc_max);
      loss += 0.5f * rank_loss(thres, (inc_neg > 0.0f) ? inc_neg : inc_max);
    } else {
      loss = 0.5f * rank_loss(thres, union_max) + 0.5f * rank_loss(thres, inc_neg);
    }
    if (lane == 0) atomicAdd(out, loss);
  }
}

extern "C" void kernel_launch(void* const* d_in, const int* in_sizes, int n_in,
                              void* d_out, int out_size, void* d_ws, size_t ws_size,
                              hipStream_t stream) {
  (void)in_sizes; (void)n_in; (void)out_size; (void)ws_size;
  const float* x = (const float*)d_in[0];
  const int* y = (const int*)d_in[1];
  const int* yn = (const int*)d_in[2];
  const void* gm = d_in[3];

  int* flag = (int*)d_ws;
  unsigned char* ws = (unsigned char*)d_ws;
  unsigned char* ws64 = ws + 64;

  probe_init_kernel<<<1, 1024, 0, stream>>>((const uint4*)gm, ws,
                                            (float*)d_out, flag);
  build_gid_kernel<<<(GM_BYTES + 255) / 256, 256, 0, stream>>>(gm, flag, ws);
  loss_kernel<<<B_ROWS, 256, 0, stream>>>(x, y, yn, ws64, (float*)d_out);
}